// Round 11
// baseline (1158.600 us; speedup 1.0000x reference)
//
#include <hip/hip_runtime.h>
#include <math.h>

// Fused semantic attention — round-8 skeleton re-fit for 4 blocks/CU.
// Round-11 theory: kernel is latency-bound with all pipes idle at 16 waves/CU
// (2 blocks). VGPR=64 already supports 8 waves/SIMD; only LDS (44 KB) blocked
// 4 blocks/CU. Changes:
//  - LDS = exactly 40960 B: padding removed, T2 XOR swizzles instead
//    (f16 col^=(row&7)<<3, f32 col^=(row&7)<<2; 16B granules preserved)
//  - rsumf aliased into Kb (dead after main loop)
//  - __launch_bounds__(512, 8) pins the 64-VGPR budget the code already fits
//  - keep: 2-barrier chunk loop, wave-split staging, cacheable out_s +
//    L2-replay out_a epilogue (round-8 win), pkrtz packs, exp2-fma.

#define BH 64
#define N 1024
#define D 64
#define TK 64
#define NC (N / TK)   // 16
#define LOG2E 1.44269504088896f
#define ESHIFT (-17.3123404907f)   // -12 * log2(e)

// XOR swizzles: spread row-strided column reads across banks, keep 16B granules
#define SWH(row, col) ((col) ^ (((row) & 7) << 3))   // f16 arrays (granule 8 halves)
#define SWS(row, col) ((col) ^ (((row) & 7) << 2))   // f32 arrays (granule 4 words)

typedef float    f32x4 __attribute__((ext_vector_type(4)));
typedef _Float16 half8 __attribute__((ext_vector_type(8)));
typedef _Float16 half4 __attribute__((ext_vector_type(4)));
typedef __fp16   fp16x2 __attribute__((ext_vector_type(2)));  // cvt_pkrtz result type

__global__ __launch_bounds__(512, 8) void attn_fused_kernel(
    const float* __restrict__ q, const float* __restrict__ k,
    const float* __restrict__ v, const float* __restrict__ qs,
    const float* __restrict__ ks, float* __restrict__ out_o,
    float* __restrict__ out_a, float* __restrict__ out_s)
{
    __shared__ __align__(16) _Float16 Kb[2][TK][64];   // 16384 B, dbuf
    __shared__ __align__(16) _Float16 Vt[2][D][64];    // 16384 B, dbuf
    __shared__ __align__(16) float    Sst[32][64];     //  8192 B
    float* rsumf = (float*)&Kb[0][0][0];               // aliased: Kb dead post-loop

    const int t  = threadIdx.x;
    const int w  = t >> 6;
    const int l  = t & 63;
    const int lr = l & 15;
    const int lg = l >> 4;
    const int qt = w >> 2;     // q 16-row tile (QK and PV)
    const int kt = w & 3;      // QK: k 16-col tile; PV: d 16-col tile

    // XCD pinning: wg%8 == XCD; 32 q-tiles of one batch share one XCD's L2.
    const int wg = blockIdx.x;
    const int b  = ((wg >> 8) << 3) | (wg & 7);
    const int q0 = ((wg >> 3) & 31) * 32;

    const size_t inb = (size_t)b * (N * D);
    const size_t sb  = (size_t)b * N * N + (size_t)q0 * N;

    // ---- Q fragment (A-operand rows = q0+qt*16+lr), pkrtz packs ----
    half8 qa[2];
    {
        const float* qp  = q  + inb + (size_t)(q0 + qt * 16 + lr) * D + lg * 8;
        const float* qsp = qs + inb + (size_t)(q0 + qt * 16 + lr) * D + lg * 8;
#pragma unroll
        for (int kst = 0; kst < 2; ++kst) {
            f32x4 a0 = *(const f32x4*)(qp + kst * 32);
            f32x4 a1 = *(const f32x4*)(qp + kst * 32 + 4);
            f32x4 c0 = *(const f32x4*)(qsp + kst * 32);
            f32x4 c1 = *(const f32x4*)(qsp + kst * 32 + 4);
            f32x4 s0 = a0 + c0, s1 = a1 + c1;
            union { half8 h8; fp16x2 h2[4]; } u;
            u.h2[0] = __builtin_amdgcn_cvt_pkrtz(s0[0], s0[1]);
            u.h2[1] = __builtin_amdgcn_cvt_pkrtz(s0[2], s0[3]);
            u.h2[2] = __builtin_amdgcn_cvt_pkrtz(s1[0], s1[1]);
            u.h2[3] = __builtin_amdgcn_cvt_pkrtz(s1[2], s1[3]);
            qa[kst] = u.h8;
        }
    }

    // ---- staging: waves 0-3 load K+KS, waves 4-7 load V (wave-uniform) ----
    const int  ts = t & 255;
    const bool kstager = (w < 4);
    f32x4 kreg[4], sreg[4], vreg[4];

    auto LOAD = [&](int kc) {   // every instr: 1KB contiguous per wave-group
        if (kstager) {
            const f32x4* kbp = (const f32x4*)(k  + inb + (size_t)kc * TK * D);
            const f32x4* sbp = (const f32x4*)(ks + inb + (size_t)kc * TK * D);
#pragma unroll
            for (int j = 0; j < 4; ++j) {
                kreg[j] = kbp[j * 256 + ts];
                sreg[j] = sbp[j * 256 + ts];
            }
        } else {
            const f32x4* vbp = (const f32x4*)(v + inb + (size_t)kc * TK * D);
#pragma unroll
            for (int j = 0; j < 4; ++j)
                vreg[j] = vbp[((ts >> 4) * 4 + j) * 16 + (ts & 15)];
        }
    };
    auto STORE = [&](int bf) {
        if (kstager) {          // fused Kf row-major, swizzled cols
#pragma unroll
            for (int j = 0; j < 4; ++j) {
                const int row = j * 16 + (ts >> 4), col = (ts & 15) * 4;
                f32x4 sm = kreg[j] + sreg[j];
                union { half4 h4; fp16x2 h2[2]; } u;
                u.h2[0] = __builtin_amdgcn_cvt_pkrtz(sm[0], sm[1]);
                u.h2[1] = __builtin_amdgcn_cvt_pkrtz(sm[2], sm[3]);
                *(half4*)&Kb[bf][row][SWH(row, col)] = u.h4;
            }
        } else {                // V 4x4 register transpose -> Vt[d][kk], swizzled
            const int br4 = (ts >> 4) * 4, bc4 = (ts & 15) * 4;
#pragma unroll
            for (int c = 0; c < 4; ++c) {
                const int row = bc4 + c;
                union { half4 h4; fp16x2 h2[2]; } u;
                u.h2[0] = __builtin_amdgcn_cvt_pkrtz(vreg[0][c], vreg[1][c]);
                u.h2[1] = __builtin_amdgcn_cvt_pkrtz(vreg[2][c], vreg[3][c]);
                *(half4*)&Vt[bf][row][SWH(row, br4)] = u.h4;
            }
        }
    };

    LOAD(0);
    STORE(0);
    __syncthreads();

    f32x4 oacc = {0.f, 0.f, 0.f, 0.f};
    float rs = 0.0f;

    for (int kc = 0; kc < NC; ++kc) {
        const int c = kc & 1;

        // --- QK^T: one 16x16 tile per wave (swizzled Kb reads) ---
        {
            const int krow = kt * 16 + lr;
            half8 kb0 = *(const half8*)&Kb[c][krow][SWH(krow, lg * 8)];
            half8 kb1 = *(const half8*)&Kb[c][krow][SWH(krow, 32 + lg * 8)];
            f32x4 ac = {0.f, 0.f, 0.f, 0.f};
            ac = __builtin_amdgcn_mfma_f32_16x16x32_f16(qa[0], kb0, ac, 0, 0, 0);
            ac = __builtin_amdgcn_mfma_f32_16x16x32_f16(qa[1], kb1, ac, 0, 0, 0);
#pragma unroll
            for (int r = 0; r < 4; ++r) {   // C/D: col=lr, row=4*lg+r
                const int srow = qt * 16 + lg * 4 + r;
                Sst[srow][SWS(srow, kt * 16 + lr)] = ac[r] * 0.125f;
            }
        }
        __syncthreads();   // Sst chunk ready

        if (kc + 1 < NC) LOAD(kc + 1);   // prefetch (consumed at STORE below)

        // --- out_s: cacheable coalesced store (L2-resident for the epilogue) ---
        {
            const int srow = t >> 4, scol = (t & 15) * 4;
            f32x4 sv = *(const f32x4*)&Sst[srow][SWS(srow, scol)];
            *(f32x4*)(out_s + sb + (size_t)srow * N + kc * TK + scol) = sv;
        }

        // --- P = exp(S-12) from Sst; PV MFMA; rowsum (kt==0 waves only) ---
#pragma unroll
        for (int kst = 0; kst < 2; ++kst) {
            const int prow = qt * 16 + lr;
            f32x4 s0 = *(const f32x4*)&Sst[prow][SWS(prow, kst * 32 + lg * 8)];
            f32x4 s1 = *(const f32x4*)&Sst[prow][SWS(prow, kst * 32 + lg * 8 + 4)];
            float e[8];
#pragma unroll
            for (int i = 0; i < 4; ++i) {
                e[i]     = __builtin_amdgcn_exp2f(__builtin_fmaf(s0[i], LOG2E, ESHIFT));
                e[i + 4] = __builtin_amdgcn_exp2f(__builtin_fmaf(s1[i], LOG2E, ESHIFT));
            }
            if (kt == 0)
                rs += ((e[0] + e[1]) + (e[2] + e[3])) + ((e[4] + e[5]) + (e[6] + e[7]));
            union { half8 h8; fp16x2 h2[4]; } u;
            u.h2[0] = __builtin_amdgcn_cvt_pkrtz(e[0], e[1]);
            u.h2[1] = __builtin_amdgcn_cvt_pkrtz(e[2], e[3]);
            u.h2[2] = __builtin_amdgcn_cvt_pkrtz(e[4], e[5]);
            u.h2[3] = __builtin_amdgcn_cvt_pkrtz(e[6], e[7]);
            const int vrow = kt * 16 + lr;
            half8 vb = *(const half8*)&Vt[c][vrow][SWH(vrow, kst * 32 + lg * 8)];
            oacc = __builtin_amdgcn_mfma_f32_16x16x32_f16(u.h8, vb, oacc, 0, 0, 0);
        }

        if (kc + 1 < NC) STORE(c ^ 1);   // ds_write staged regs
        __syncthreads();   // staging visible; Sst/Kb/Vt reads complete
    }

    // ---- rowsum finalize (kt==0 waves hold lg-group partials) ----
    // rsumf aliases Kb: all Kb reads are behind the loop-end barrier.
    if (kt == 0) {
        rs += __shfl_xor(rs, 16);
        rs += __shfl_xor(rs, 32);
        if (l < 16) rsumf[qt * 16 + l] = rs;
    }
    __syncthreads();
    if (t < 32) rsumf[t] = 1.0f / rsumf[t];
    __syncthreads();

    // ---- O: scale into Sst, coalesced NT store ----
#pragma unroll
    for (int r = 0; r < 4; ++r) {
        const int srow = qt * 16 + lg * 4 + r;
        Sst[srow][SWS(srow, kt * 16 + lr)] = oacc[r] * rsumf[srow];
    }
    __syncthreads();
    {
        const int srow = t >> 4, scol = (t & 15) * 4;
        f32x4 ov = *(const f32x4*)&Sst[srow][SWS(srow, scol)];
        __builtin_nontemporal_store(ov,
            (f32x4*)(out_o + inb + (size_t)(q0 + srow) * D + scol));
    }

    // ---- out_a epilogue: replay own out_s slice (L2/L3-hot), exp*inv, NT ----
    {
        const int   arow = t >> 4;
        const int   ac0  = (t & 15) * 4;
        const float iva  = rsumf[arow];
        const float* sp  = out_s + sb + (size_t)arow * N + ac0;
        float*       ap  = out_a + sb + (size_t)arow * N + ac0;
#pragma unroll 4
        for (int cb = 0; cb < NC; ++cb) {
            f32x4 sv = *(const f32x4*)(sp + cb * TK);
            f32x4 av;
#pragma unroll
            for (int i = 0; i < 4; ++i)
                av[i] = __builtin_amdgcn_exp2f(__builtin_fmaf(sv[i], LOG2E, ESHIFT)) * iva;
            __builtin_nontemporal_store(av, (f32x4*)(ap + cb * TK));
        }
    }
}

extern "C" void kernel_launch(void* const* d_in, const int* in_sizes, int n_in,
                              void* d_out, int out_size, void* d_ws, size_t ws_size,
                              hipStream_t stream) {
    const float* q  = (const float*)d_in[0];
    const float* k  = (const float*)d_in[1];
    const float* v  = (const float*)d_in[2];
    const float* qs = (const float*)d_in[3];
    const float* ks = (const float*)d_in[4];

    float* out_o = (float*)d_out;                       // [64,1024,64]
    float* out_a = out_o + (size_t)BH * N * D;          // [64,1024,1024]
    float* out_s = out_a + (size_t)BH * N * N;          // [64,1024,1024]

    attn_fused_kernel<<<dim3(BH * (N / 32)), dim3(512), 0, stream>>>(
        q, k, v, qs, ks, out_o, out_a, out_s);
}

// Round 12
// 769.254 us; speedup vs baseline: 1.5061x; 1.5061x over previous
//
#include <hip/hip_runtime.h>
#include <math.h>

// Fused semantic attention — round-8 body, single-buffered staging for occupancy.
// Round-12: round 11 proved 4 blocks/CU schedulable (occ 88%) but launch_bounds
// (512,8) forced VGPR=32 -> ~2 GB spill traffic; and the hand swizzle was wrong
// for Vt's stride-4-row writes (1.9e7 conflicts). Revert both. Instead: keep
// natural VGPR (~64, launch_bounds(512,2)) + verified padded-68 layout, and cut
// LDS 44 -> 25.7 KB by SINGLE-buffering Kb/Vt (dbuf was proven useless in r10).
// Loop: QK -> barA -> out_s+PROC -> barB -> STORE(next)+LOAD(next2) -> barC.
// This is also the decisive occupancy experiment: LDS no longer binds; if occ
// stays ~45% at VGPR=64, the VGPR->wave map is the cap and round 13 cuts regs.

#define BH 64
#define N 1024
#define D 64
#define TK 64
#define NC (N / TK)   // 16
#define KSTR 68       // f16 row stride: verified ~65K conflicts (rounds 6-8)
#define SSTR 68       // f32 row stride
#define LOG2E 1.44269504088896f
#define ESHIFT (-17.3123404907f)   // -12 * log2(e)

typedef float    f32x4 __attribute__((ext_vector_type(4)));
typedef _Float16 half8 __attribute__((ext_vector_type(8)));
typedef _Float16 half4 __attribute__((ext_vector_type(4)));
typedef __fp16   fp16x2 __attribute__((ext_vector_type(2)));  // cvt_pkrtz result

__global__ __launch_bounds__(512, 2) void attn_fused_kernel(
    const float* __restrict__ q, const float* __restrict__ k,
    const float* __restrict__ v, const float* __restrict__ qs,
    const float* __restrict__ ks, float* __restrict__ out_o,
    float* __restrict__ out_a, float* __restrict__ out_s)
{
    __shared__ __align__(16) _Float16 Kb[TK][KSTR];   // 8704 B, single buffer
    __shared__ __align__(16) _Float16 Vt[D][KSTR];    // 8704 B, single buffer
    __shared__ __align__(16) float    Sst[32][SSTR];  // 8704 B
    __shared__ float rsumf[32];                       //  128 B   (total ~25.7 KB)

    const int t  = threadIdx.x;
    const int w  = t >> 6;
    const int l  = t & 63;
    const int lr = l & 15;
    const int lg = l >> 4;
    const int qt = w >> 2;     // q 16-row tile (QK and PV)
    const int kt = w & 3;      // QK: k 16-col tile; PV: d 16-col tile

    // XCD pinning: wg%8 == XCD; 32 q-tiles of one batch share one XCD's L2.
    const int wg = blockIdx.x;
    const int b  = ((wg >> 8) << 3) | (wg & 7);
    const int q0 = ((wg >> 3) & 31) * 32;

    const size_t inb = (size_t)b * (N * D);
    const size_t sb  = (size_t)b * N * N + (size_t)q0 * N;

    // ---- Q fragment (A-operand rows = q0+qt*16+lr), pkrtz packs ----
    half8 qa[2];
    {
        const float* qp  = q  + inb + (size_t)(q0 + qt * 16 + lr) * D + lg * 8;
        const float* qsp = qs + inb + (size_t)(q0 + qt * 16 + lr) * D + lg * 8;
#pragma unroll
        for (int kst = 0; kst < 2; ++kst) {
            f32x4 a0 = *(const f32x4*)(qp + kst * 32);
            f32x4 a1 = *(const f32x4*)(qp + kst * 32 + 4);
            f32x4 c0 = *(const f32x4*)(qsp + kst * 32);
            f32x4 c1 = *(const f32x4*)(qsp + kst * 32 + 4);
            f32x4 s0 = a0 + c0, s1 = a1 + c1;
            union { half8 h8; fp16x2 h2[4]; } u;
            u.h2[0] = __builtin_amdgcn_cvt_pkrtz(s0[0], s0[1]);
            u.h2[1] = __builtin_amdgcn_cvt_pkrtz(s0[2], s0[3]);
            u.h2[2] = __builtin_amdgcn_cvt_pkrtz(s1[0], s1[1]);
            u.h2[3] = __builtin_amdgcn_cvt_pkrtz(s1[2], s1[3]);
            qa[kst] = u.h8;
        }
    }

    // ---- staging: waves 0-3 load K+KS, waves 4-7 load V (wave-uniform) ----
    const int  ts = t & 255;
    const bool kstager = (w < 4);
    f32x4 kreg[4], sreg[4], vreg[4];

    auto LOAD = [&](int kc) {   // every instr: 1KB contiguous per wave-group
        if (kstager) {
            const f32x4* kbp = (const f32x4*)(k  + inb + (size_t)kc * TK * D);
            const f32x4* sbp = (const f32x4*)(ks + inb + (size_t)kc * TK * D);
#pragma unroll
            for (int j = 0; j < 4; ++j) {
                kreg[j] = kbp[j * 256 + ts];
                sreg[j] = sbp[j * 256 + ts];
            }
        } else {
            const f32x4* vbp = (const f32x4*)(v + inb + (size_t)kc * TK * D);
#pragma unroll
            for (int j = 0; j < 4; ++j)
                vreg[j] = vbp[((ts >> 4) * 4 + j) * 16 + (ts & 15)];
        }
    };
    auto STORE = [&]() {
        if (kstager) {          // fused Kf row-major, pkrtz packs
#pragma unroll
            for (int j = 0; j < 4; ++j) {
                const int row = j * 16 + (ts >> 4), col = (ts & 15) * 4;
                f32x4 sm = kreg[j] + sreg[j];
                union { half4 h4; fp16x2 h2[2]; } u;
                u.h2[0] = __builtin_amdgcn_cvt_pkrtz(sm[0], sm[1]);
                u.h2[1] = __builtin_amdgcn_cvt_pkrtz(sm[2], sm[3]);
                *(half4*)&Kb[row][col] = u.h4;
            }
        } else {                // V 4x4 register transpose -> Vt[d][kk]
            const int br4 = (ts >> 4) * 4, bc4 = (ts & 15) * 4;
#pragma unroll
            for (int c = 0; c < 4; ++c) {
                union { half4 h4; fp16x2 h2[2]; } u;
                u.h2[0] = __builtin_amdgcn_cvt_pkrtz(vreg[0][c], vreg[1][c]);
                u.h2[1] = __builtin_amdgcn_cvt_pkrtz(vreg[2][c], vreg[3][c]);
                *(half4*)&Vt[bc4 + c][br4] = u.h4;
            }
        }
    };

    // ---- prologue: stage chunk 0, prefetch chunk 1 into regs ----
    LOAD(0);
    STORE();
    LOAD(1);
    __syncthreads();

    f32x4 oacc = {0.f, 0.f, 0.f, 0.f};
    float rs = 0.0f;

    for (int kc = 0; kc < NC; ++kc) {
        // --- QK^T: one 16x16 tile per wave ---
        {
            half8 kb0 = *(const half8*)&Kb[kt * 16 + lr][lg * 8];
            half8 kb1 = *(const half8*)&Kb[kt * 16 + lr][32 + lg * 8];
            f32x4 ac = {0.f, 0.f, 0.f, 0.f};
            ac = __builtin_amdgcn_mfma_f32_16x16x32_f16(qa[0], kb0, ac, 0, 0, 0);
            ac = __builtin_amdgcn_mfma_f32_16x16x32_f16(qa[1], kb1, ac, 0, 0, 0);
#pragma unroll
            for (int r = 0; r < 4; ++r)   // C/D: col=lr, row=4*lg+r
                Sst[qt * 16 + lg * 4 + r][kt * 16 + lr] = ac[r] * 0.125f;
        }
        __syncthreads();   // barA: Sst ready; Kb reads complete

        // --- out_s: cacheable coalesced (L2-resident for the epilogue) ---
        {
            f32x4 sv = *(const f32x4*)&Sst[t >> 4][(t & 15) * 4];
            *(f32x4*)(out_s + sb + (size_t)(t >> 4) * N + kc * TK + (t & 15) * 4) = sv;
        }

        // --- P = exp(S-12); PV MFMA; rowsum (kt==0 waves only) ---
#pragma unroll
        for (int kst = 0; kst < 2; ++kst) {
            f32x4 s0 = *(const f32x4*)&Sst[qt * 16 + lr][kst * 32 + lg * 8];
            f32x4 s1 = *(const f32x4*)&Sst[qt * 16 + lr][kst * 32 + lg * 8 + 4];
            float e[8];
#pragma unroll
            for (int i = 0; i < 4; ++i) {
                e[i]     = __builtin_amdgcn_exp2f(__builtin_fmaf(s0[i], LOG2E, ESHIFT));
                e[i + 4] = __builtin_amdgcn_exp2f(__builtin_fmaf(s1[i], LOG2E, ESHIFT));
            }
            if (kt == 0)
                rs += ((e[0] + e[1]) + (e[2] + e[3])) + ((e[4] + e[5]) + (e[6] + e[7]));
            union { half8 h8; fp16x2 h2[4]; } u;
            u.h2[0] = __builtin_amdgcn_cvt_pkrtz(e[0], e[1]);
            u.h2[1] = __builtin_amdgcn_cvt_pkrtz(e[2], e[3]);
            u.h2[2] = __builtin_amdgcn_cvt_pkrtz(e[4], e[5]);
            u.h2[3] = __builtin_amdgcn_cvt_pkrtz(e[6], e[7]);
            half8 vb = *(const half8*)&Vt[kt * 16 + lr][kst * 32 + lg * 8];
            oacc = __builtin_amdgcn_mfma_f32_16x16x32_f16(u.h8, vb, oacc, 0, 0, 0);
        }

        if (kc + 1 < NC) {
            __syncthreads();            // barB: Vt/Sst reads complete
            STORE();                    // stage chunk kc+1 (regs from last LOAD)
            if (kc + 2 < NC) LOAD(kc + 2);   // refill regs; lands during next window
            __syncthreads();            // barC: staging visible
        }
    }

    // ---- rowsum finalize (kt==0 waves hold lg-group partials) ----
    if (kt == 0) {
        rs += __shfl_xor(rs, 16);
        rs += __shfl_xor(rs, 32);
        if (l < 16) rsumf[qt * 16 + l] = rs;
    }
    __syncthreads();
    if (t < 32) rsumf[t] = 1.0f / rsumf[t];
    __syncthreads();

    // ---- O: scale into Sst, coalesced NT store ----
#pragma unroll
    for (int r = 0; r < 4; ++r)
        Sst[qt * 16 + lg * 4 + r][kt * 16 + lr] =
            oacc[r] * rsumf[qt * 16 + lg * 4 + r];
    __syncthreads();
    {
        f32x4 ov = *(const f32x4*)&Sst[t >> 4][(t & 15) * 4];
        __builtin_nontemporal_store(ov,
            (f32x4*)(out_o + inb + (size_t)(q0 + (t >> 4)) * D + (t & 15) * 4));
    }

    // ---- out_a epilogue: replay own out_s slice (L2/L3-hot), exp*inv, NT ----
    {
        const int   arow = t >> 4;
        const int   ac0  = (t & 15) * 4;
        const float iva  = rsumf[arow];
        const float* sp  = out_s + sb + (size_t)arow * N + ac0;
        float*       ap  = out_a + sb + (size_t)arow * N + ac0;
#pragma unroll 4
        for (int cb = 0; cb < NC; ++cb) {
            f32x4 sv = *(const f32x4*)(sp + cb * TK);
            f32x4 av;
#pragma unroll
            for (int i = 0; i < 4; ++i)
                av[i] = __builtin_amdgcn_exp2f(__builtin_fmaf(sv[i], LOG2E, ESHIFT)) * iva;
            __builtin_nontemporal_store(av, (f32x4*)(ap + cb * TK));
        }
    }
}

extern "C" void kernel_launch(void* const* d_in, const int* in_sizes, int n_in,
                              void* d_out, int out_size, void* d_ws, size_t ws_size,
                              hipStream_t stream) {
    const float* q  = (const float*)d_in[0];
    const float* k  = (const float*)d_in[1];
    const float* v  = (const float*)d_in[2];
    const float* qs = (const float*)d_in[3];
    const float* ks = (const float*)d_in[4];

    float* out_o = (float*)d_out;                       // [64,1024,64]
    float* out_a = out_o + (size_t)BH * N * D;          // [64,1024,1024]
    float* out_s = out_a + (size_t)BH * N * N;          // [64,1024,1024]

    attn_fused_kernel<<<dim3(BH * (N / 32)), dim3(512), 0, stream>>>(
        q, k, v, qs, ks, out_o, out_a, out_s);
}

// Round 15
// 756.530 us; speedup vs baseline: 1.5315x; 1.0168x over previous
//
#include <hip/hip_runtime.h>
#include <math.h>

// Fused semantic attention — T4 experiment, data-flow CORRECTED.
// Rounds 13/14 failed with IDENTICAL absmax -> deterministic data bug, not a
// race: LOAD(kc+2) was issued before STORE(c^1) consumed the regs of
// LOAD(kc+1), so chunk kc+1 was staged with chunk kc+2's K/V. Fixed order:
//   QK -> STORE(c^1) -> LOAD(kc+2) -> BAR_A -> out_s+PROC -> BAR_B.
// The experiment itself is unchanged: no vmcnt(0) drain anywhere in the main
// loop (LDS-only barriers: fused {s_waitcnt lgkmcnt(0); s_barrier} pinned by
// sched_barrier(0) per rule #18); global loads/stores ride through barriers.
// Kb/Vt double-buffered, Sst single; 2 LDS-barriers/chunk; LDS 44 KB.

#define BH 64
#define N 1024
#define D 64
#define TK 64
#define NC (N / TK)   // 16
#define KSTR 68       // f16 row stride: verified ~65K conflicts
#define SSTR 68       // f32 row stride
#define LOG2E 1.44269504088896f
#define ESHIFT (-17.3123404907f)   // -12 * log2(e)

// LDS-only barrier: drain LDS ops + workgroup barrier in ONE asm block,
// bracketed by sched_barrier(0) so nothing is scheduled across it.
#define LGKM_BAR() do {                                              \
    __builtin_amdgcn_sched_barrier(0);                               \
    asm volatile("s_waitcnt lgkmcnt(0)\n\ts_barrier" ::: "memory");  \
    __builtin_amdgcn_sched_barrier(0);                               \
} while (0)

typedef float    f32x4 __attribute__((ext_vector_type(4)));
typedef _Float16 half8 __attribute__((ext_vector_type(8)));
typedef _Float16 half4 __attribute__((ext_vector_type(4)));
typedef __fp16   fp16x2 __attribute__((ext_vector_type(2)));  // cvt_pkrtz result

__global__ __launch_bounds__(512, 4) void attn_fused_kernel(
    const float* __restrict__ q, const float* __restrict__ k,
    const float* __restrict__ v, const float* __restrict__ qs,
    const float* __restrict__ ks, float* __restrict__ out_o,
    float* __restrict__ out_a, float* __restrict__ out_s)
{
    __shared__ __align__(16) _Float16 Kb[2][TK][KSTR];  // 17.4 KB dbuf
    __shared__ __align__(16) _Float16 Vt[2][D][KSTR];   // 17.4 KB dbuf
    __shared__ __align__(16) float    Sst[32][SSTR];    //  8.7 KB single
    __shared__ float rsumf[32];

    const int t  = threadIdx.x;
    const int w  = t >> 6;
    const int l  = t & 63;
    const int lr = l & 15;
    const int lg = l >> 4;
    const int qt = w >> 2;     // q 16-row tile (QK and PV)
    const int kt = w & 3;      // QK: k 16-col tile; PV: d 16-col tile

    // XCD pinning: wg%8 == XCD; 32 q-tiles of one batch share one XCD's L2.
    const int wg = blockIdx.x;
    const int b  = ((wg >> 8) << 3) | (wg & 7);
    const int q0 = ((wg >> 3) & 31) * 32;

    const size_t inb = (size_t)b * (N * D);
    const size_t sb  = (size_t)b * N * N + (size_t)q0 * N;

    // ---- Q fragment (A-operand rows = q0+qt*16+lr), pkrtz packs ----
    half8 qa[2];
    {
        const float* qp  = q  + inb + (size_t)(q0 + qt * 16 + lr) * D + lg * 8;
        const float* qsp = qs + inb + (size_t)(q0 + qt * 16 + lr) * D + lg * 8;
#pragma unroll
        for (int kst = 0; kst < 2; ++kst) {
            f32x4 a0 = *(const f32x4*)(qp + kst * 32);
            f32x4 a1 = *(const f32x4*)(qp + kst * 32 + 4);
            f32x4 c0 = *(const f32x4*)(qsp + kst * 32);
            f32x4 c1 = *(const f32x4*)(qsp + kst * 32 + 4);
            f32x4 s0 = a0 + c0, s1 = a1 + c1;
            union { half8 h8; fp16x2 h2[4]; } u;
            u.h2[0] = __builtin_amdgcn_cvt_pkrtz(s0[0], s0[1]);
            u.h2[1] = __builtin_amdgcn_cvt_pkrtz(s0[2], s0[3]);
            u.h2[2] = __builtin_amdgcn_cvt_pkrtz(s1[0], s1[1]);
            u.h2[3] = __builtin_amdgcn_cvt_pkrtz(s1[2], s1[3]);
            qa[kst] = u.h8;
        }
    }

    // ---- staging: waves 0-3 load K+KS, waves 4-7 load V (wave-uniform) ----
    const int  ts = t & 255;
    const bool kstager = (w < 4);
    f32x4 kreg[4], sreg[4], vreg[4];

    auto LOAD = [&](int kc) {   // every instr: 1KB contiguous per wave-group
        if (kstager) {
            const f32x4* kbp = (const f32x4*)(k  + inb + (size_t)kc * TK * D);
            const f32x4* sbp = (const f32x4*)(ks + inb + (size_t)kc * TK * D);
#pragma unroll
            for (int j = 0; j < 4; ++j) {
                kreg[j] = kbp[j * 256 + ts];
                sreg[j] = sbp[j * 256 + ts];
            }
        } else {
            const f32x4* vbp = (const f32x4*)(v + inb + (size_t)kc * TK * D);
#pragma unroll
            for (int j = 0; j < 4; ++j)
                vreg[j] = vbp[((ts >> 4) * 4 + j) * 16 + (ts & 15)];
        }
    };
    auto STORE = [&](int bf) {
        if (kstager) {          // fused Kf row-major, pkrtz packs
#pragma unroll
            for (int j = 0; j < 4; ++j) {
                const int row = j * 16 + (ts >> 4), col = (ts & 15) * 4;
                f32x4 sm = kreg[j] + sreg[j];
                union { half4 h4; fp16x2 h2[2]; } u;
                u.h2[0] = __builtin_amdgcn_cvt_pkrtz(sm[0], sm[1]);
                u.h2[1] = __builtin_amdgcn_cvt_pkrtz(sm[2], sm[3]);
                *(half4*)&Kb[bf][row][col] = u.h4;
            }
        } else {                // V 4x4 register transpose -> Vt[d][kk]
            const int br4 = (ts >> 4) * 4, bc4 = (ts & 15) * 4;
#pragma unroll
            for (int c = 0; c < 4; ++c) {
                union { half4 h4; fp16x2 h2[2]; } u;
                u.h2[0] = __builtin_amdgcn_cvt_pkrtz(vreg[0][c], vreg[1][c]);
                u.h2[1] = __builtin_amdgcn_cvt_pkrtz(vreg[2][c], vreg[3][c]);
                *(half4*)&Vt[bf][bc4 + c][br4] = u.h4;
            }
        }
    };

    // ---- prologue: stage chunk 0 into buf 0; prefetch chunk 1 to regs ----
    LOAD(0);
    STORE(0);
    LOAD(1);
    __syncthreads();   // full barrier once (prologue)

    f32x4 oacc = {0.f, 0.f, 0.f, 0.f};
    float rs = 0.0f;

    for (int kc = 0; kc < NC; ++kc) {
        const int c = kc & 1;

        // --- QK^T from Kb[c] -> Sst (ds ops only) ---
        {
            half8 kb0 = *(const half8*)&Kb[c][kt * 16 + lr][lg * 8];
            half8 kb1 = *(const half8*)&Kb[c][kt * 16 + lr][32 + lg * 8];
            f32x4 ac = {0.f, 0.f, 0.f, 0.f};
            ac = __builtin_amdgcn_mfma_f32_16x16x32_f16(qa[0], kb0, ac, 0, 0, 0);
            ac = __builtin_amdgcn_mfma_f32_16x16x32_f16(qa[1], kb1, ac, 0, 0, 0);
#pragma unroll
            for (int r = 0; r < 4; ++r)   // C/D: col=lr, row=4*lg+r
                Sst[qt * 16 + lg * 4 + r][kt * 16 + lr] = ac[r] * 0.125f;
        }

        // --- stage chunk kc+1 into buf c^1 FIRST (consumes LOAD(kc+1) regs;
        //     Kb/Vt[c^1] last read in chunk kc-1, barrier-separated) ---
        if (kc + 1 < NC) STORE(c ^ 1);
        // --- THEN refill regs for chunk kc+2 (rides through barriers) ---
        if (kc + 2 < NC) LOAD(kc + 2);

        LGKM_BAR();   // A_k: Sst + staging visible; Kb[c] reads drained

        // --- out_s: cacheable coalesced store; never awaited in-loop ---
        {
            f32x4 sv = *(const f32x4*)&Sst[t >> 4][(t & 15) * 4];
            *(f32x4*)(out_s + sb + (size_t)(t >> 4) * N + kc * TK + (t & 15) * 4) = sv;
        }

        // --- P = exp(S-12); PV MFMA from Vt[c]; rowsum (kt==0 waves) ---
#pragma unroll
        for (int kst = 0; kst < 2; ++kst) {
            f32x4 s0 = *(const f32x4*)&Sst[qt * 16 + lr][kst * 32 + lg * 8];
            f32x4 s1 = *(const f32x4*)&Sst[qt * 16 + lr][kst * 32 + lg * 8 + 4];
            float e[8];
#pragma unroll
            for (int i = 0; i < 4; ++i) {
                e[i]     = __builtin_amdgcn_exp2f(__builtin_fmaf(s0[i], LOG2E, ESHIFT));
                e[i + 4] = __builtin_amdgcn_exp2f(__builtin_fmaf(s1[i], LOG2E, ESHIFT));
            }
            if (kt == 0)
                rs += ((e[0] + e[1]) + (e[2] + e[3])) + ((e[4] + e[5]) + (e[6] + e[7]));
            union { half8 h8; fp16x2 h2[4]; } u;
            u.h2[0] = __builtin_amdgcn_cvt_pkrtz(e[0], e[1]);
            u.h2[1] = __builtin_amdgcn_cvt_pkrtz(e[2], e[3]);
            u.h2[2] = __builtin_amdgcn_cvt_pkrtz(e[4], e[5]);
            u.h2[3] = __builtin_amdgcn_cvt_pkrtz(e[6], e[7]);
            half8 vb = *(const half8*)&Vt[c][kt * 16 + lr][kst * 32 + lg * 8];
            oacc = __builtin_amdgcn_mfma_f32_16x16x32_f16(u.h8, vb, oacc, 0, 0, 0);
        }

        LGKM_BAR();   // B_k: Sst/Vt reads drained; next chunk may overwrite Sst
                      // and read Kb/Vt[c^1]
    }

    // ---- rowsum finalize (kt==0 waves hold lg-group partials) ----
    if (kt == 0) {
        rs += __shfl_xor(rs, 16);
        rs += __shfl_xor(rs, 32);
        if (l < 16) rsumf[qt * 16 + l] = rs;
    }
    __syncthreads();
    if (t < 32) rsumf[t] = 1.0f / rsumf[t];
    __syncthreads();

    // ---- O: scale into Sst, coalesced NT store ----
#pragma unroll
    for (int r = 0; r < 4; ++r)
        Sst[qt * 16 + lg * 4 + r][kt * 16 + lr] =
            oacc[r] * rsumf[qt * 16 + lg * 4 + r];
    __syncthreads();
    {
        f32x4 ov = *(const f32x4*)&Sst[t >> 4][(t & 15) * 4];
        __builtin_nontemporal_store(ov,
            (f32x4*)(out_o + inb + (size_t)(q0 + (t >> 4)) * D + (t & 15) * 4));
    }

    // ---- out_a epilogue: replay own out_s slice (L2/L3-hot), exp*inv, NT ----
    {
        const int   arow = t >> 4;
        const int   ac0  = (t & 15) * 4;
        const float iva  = rsumf[arow];
        const float* sp  = out_s + sb + (size_t)arow * N + ac0;
        float*       ap  = out_a + sb + (size_t)arow * N + ac0;
#pragma unroll 4
        for (int cb = 0; cb < NC; ++cb) {
            f32x4 sv = *(const f32x4*)(sp + cb * TK);
            f32x4 av;
#pragma unroll
            for (int i = 0; i < 4; ++i)
                av[i] = __builtin_amdgcn_exp2f(__builtin_fmaf(sv[i], LOG2E, ESHIFT)) * iva;
            __builtin_nontemporal_store(av, (f32x4*)(ap + cb * TK));
        }
    }
}

extern "C" void kernel_launch(void* const* d_in, const int* in_sizes, int n_in,
                              void* d_out, int out_size, void* d_ws, size_t ws_size,
                              hipStream_t stream) {
    const float* q  = (const float*)d_in[0];
    const float* k  = (const float*)d_in[1];
    const float* v  = (const float*)d_in[2];
    const float* qs = (const float*)d_in[3];
    const float* ks = (const float*)d_in[4];

    float* out_o = (float*)d_out;                       // [64,1024,64]
    float* out_a = out_o + (size_t)BH * N * D;          // [64,1024,1024]
    float* out_s = out_a + (size_t)BH * N * N;          // [64,1024,1024]

    attn_fused_kernel<<<dim3(BH * (N / 32)), dim3(512), 0, stream>>>(
        q, k, v, qs, ks, out_o, out_a, out_s);
}

// Round 16
// 718.610 us; speedup vs baseline: 1.6123x; 1.0528x over previous
//
#include <hip/hip_runtime.h>
#include <math.h>

// Fused semantic attention — pure-TLP version: 4 blocks/CU, no pipelining.
// Ledger: every scheduling lever (barrier count, dbuf, vmcnt drains) is null;
// the one surviving correlation is occupancy -> effective BW (r11: 4 blocks/CU
// sustained 3.8 TB/s vs 2.1 at <=3 blocks; the harness fill hits 6.3 TB/s on
// TLP alone). 4 blocks/CU needs VGPR<=64 (allocator naturally lands at 64 on
// this body) AND LDS<=40 KB (r8/r15's 44 KB was the blocker; r12's prefetch
// regs likely broke 64). So: single-buffered Kb/Vt/Sst = 26.2 KB, NO register
// prefetch (staging loads consumed immediately, 16 transient regs), plain
// __syncthreads (r15: drains are free), 3 barriers/chunk. Keep: pkrtz packs,
// exp2-fma, cacheable out_s + L2-replay out_a epilogue, XCD pinning.

#define BH 64
#define N 1024
#define D 64
#define TK 64
#define NC (N / TK)   // 16
#define KSTR 68       // f16 row stride: verified ~65K conflicts
#define SSTR 68       // f32 row stride
#define LOG2E 1.44269504088896f
#define ESHIFT (-17.3123404907f)   // -12 * log2(e)

typedef float    f32x4 __attribute__((ext_vector_type(4)));
typedef _Float16 half8 __attribute__((ext_vector_type(8)));
typedef _Float16 half4 __attribute__((ext_vector_type(4)));
typedef __fp16   fp16x2 __attribute__((ext_vector_type(2)));  // cvt_pkrtz result

__global__ __launch_bounds__(512, 4) void attn_fused_kernel(
    const float* __restrict__ q, const float* __restrict__ k,
    const float* __restrict__ v, const float* __restrict__ qs,
    const float* __restrict__ ks, float* __restrict__ out_o,
    float* __restrict__ out_a, float* __restrict__ out_s)
{
    __shared__ __align__(16) _Float16 Kb[TK][KSTR];   // 8704 B single
    __shared__ __align__(16) _Float16 Vt[D][KSTR];    // 8704 B single
    __shared__ __align__(16) float    Sst[32][SSTR];  // 8704 B single
    __shared__ float rsumf[32];                       // total ~25.7 KB

    const int t  = threadIdx.x;
    const int w  = t >> 6;
    const int l  = t & 63;
    const int lr = l & 15;
    const int lg = l >> 4;
    const int qt = w >> 2;     // q 16-row tile (QK and PV)
    const int kt = w & 3;      // QK: k 16-col tile; PV: d 16-col tile

    // XCD pinning: wg%8 == XCD; 32 q-tiles of one batch share one XCD's L2.
    const int wg = blockIdx.x;
    const int b  = ((wg >> 8) << 3) | (wg & 7);
    const int q0 = ((wg >> 3) & 31) * 32;

    const size_t inb = (size_t)b * (N * D);
    const size_t sb  = (size_t)b * N * N + (size_t)q0 * N;

    // ---- Q fragment (A-operand rows = q0+qt*16+lr), pkrtz packs ----
    half8 qa[2];
    {
        const float* qp  = q  + inb + (size_t)(q0 + qt * 16 + lr) * D + lg * 8;
        const float* qsp = qs + inb + (size_t)(q0 + qt * 16 + lr) * D + lg * 8;
#pragma unroll
        for (int kst = 0; kst < 2; ++kst) {
            f32x4 a0 = *(const f32x4*)(qp + kst * 32);
            f32x4 a1 = *(const f32x4*)(qp + kst * 32 + 4);
            f32x4 c0 = *(const f32x4*)(qsp + kst * 32);
            f32x4 c1 = *(const f32x4*)(qsp + kst * 32 + 4);
            f32x4 s0 = a0 + c0, s1 = a1 + c1;
            union { half8 h8; fp16x2 h2[4]; } u;
            u.h2[0] = __builtin_amdgcn_cvt_pkrtz(s0[0], s0[1]);
            u.h2[1] = __builtin_amdgcn_cvt_pkrtz(s0[2], s0[3]);
            u.h2[2] = __builtin_amdgcn_cvt_pkrtz(s1[0], s1[1]);
            u.h2[3] = __builtin_amdgcn_cvt_pkrtz(s1[2], s1[3]);
            qa[kst] = u.h8;
        }
    }

    // ---- staging: waves 0-3 stage K+KS, waves 4-7 stage V (wave-uniform).
    //      No prefetch: load -> immediately convert/store (16 transient VGPR).
    const int  ts = t & 255;
    const bool kstager = (w < 4);

    auto STAGE = [&](int kc) {
        if (kstager) {          // fused Kf = K + KS, row-major; two half-chunks
            const f32x4* kbp = (const f32x4*)(k  + inb + (size_t)kc * TK * D);
            const f32x4* sbp = (const f32x4*)(ks + inb + (size_t)kc * TK * D);
#pragma unroll
            for (int h = 0; h < 2; ++h) {
                f32x4 k0 = kbp[(2 * h)     * 256 + ts];
                f32x4 k1 = kbp[(2 * h + 1) * 256 + ts];
                f32x4 s0 = sbp[(2 * h)     * 256 + ts];
                f32x4 s1 = sbp[(2 * h + 1) * 256 + ts];
                f32x4 m0 = k0 + s0, m1 = k1 + s1;
                const int row0 = (2 * h) * 16 + (ts >> 4);
                const int col  = (ts & 15) * 4;
                union { half4 h4; fp16x2 h2[2]; } u0, u1;
                u0.h2[0] = __builtin_amdgcn_cvt_pkrtz(m0[0], m0[1]);
                u0.h2[1] = __builtin_amdgcn_cvt_pkrtz(m0[2], m0[3]);
                u1.h2[0] = __builtin_amdgcn_cvt_pkrtz(m1[0], m1[1]);
                u1.h2[1] = __builtin_amdgcn_cvt_pkrtz(m1[2], m1[3]);
                *(half4*)&Kb[row0][col]      = u0.h4;
                *(half4*)&Kb[row0 + 16][col] = u1.h4;
            }
        } else {                // V 4x4 register transpose -> Vt[d][kk]
            const f32x4* vbp = (const f32x4*)(v + inb + (size_t)kc * TK * D);
            f32x4 vr0 = vbp[((ts >> 4) * 4 + 0) * 16 + (ts & 15)];
            f32x4 vr1 = vbp[((ts >> 4) * 4 + 1) * 16 + (ts & 15)];
            f32x4 vr2 = vbp[((ts >> 4) * 4 + 2) * 16 + (ts & 15)];
            f32x4 vr3 = vbp[((ts >> 4) * 4 + 3) * 16 + (ts & 15)];
            const int br4 = (ts >> 4) * 4, bc4 = (ts & 15) * 4;
#pragma unroll
            for (int c = 0; c < 4; ++c) {
                union { half4 h4; fp16x2 h2[2]; } u;
                u.h2[0] = __builtin_amdgcn_cvt_pkrtz(vr0[c], vr1[c]);
                u.h2[1] = __builtin_amdgcn_cvt_pkrtz(vr2[c], vr3[c]);
                *(half4*)&Vt[bc4 + c][br4] = u.h4;
            }
        }
    };

    f32x4 oacc = {0.f, 0.f, 0.f, 0.f};
    float rs = 0.0f;

    for (int kc = 0; kc < NC; ++kc) {
        __syncthreads();   // bar0: prior chunk's Kb/Vt/Sst reads complete
        STAGE(kc);
        __syncthreads();   // bar1: staging visible

        // --- QK^T: one 16x16 tile per wave ---
        {
            half8 kb0 = *(const half8*)&Kb[kt * 16 + lr][lg * 8];
            half8 kb1 = *(const half8*)&Kb[kt * 16 + lr][32 + lg * 8];
            f32x4 ac = {0.f, 0.f, 0.f, 0.f};
            ac = __builtin_amdgcn_mfma_f32_16x16x32_f16(qa[0], kb0, ac, 0, 0, 0);
            ac = __builtin_amdgcn_mfma_f32_16x16x32_f16(qa[1], kb1, ac, 0, 0, 0);
#pragma unroll
            for (int r = 0; r < 4; ++r)   // C/D: col=lr, row=4*lg+r
                Sst[qt * 16 + lg * 4 + r][kt * 16 + lr] = ac[r] * 0.125f;
        }
        __syncthreads();   // bar2: Sst visible

        // --- out_s: cacheable coalesced (L2-resident for the epilogue) ---
        {
            f32x4 sv = *(const f32x4*)&Sst[t >> 4][(t & 15) * 4];
            *(f32x4*)(out_s + sb + (size_t)(t >> 4) * N + kc * TK + (t & 15) * 4) = sv;
        }

        // --- P = exp(S-12); PV MFMA; rowsum (kt==0 waves only) ---
#pragma unroll
        for (int kst = 0; kst < 2; ++kst) {
            f32x4 s0 = *(const f32x4*)&Sst[qt * 16 + lr][kst * 32 + lg * 8];
            f32x4 s1 = *(const f32x4*)&Sst[qt * 16 + lr][kst * 32 + lg * 8 + 4];
            float e[8];
#pragma unroll
            for (int i = 0; i < 4; ++i) {
                e[i]     = __builtin_amdgcn_exp2f(__builtin_fmaf(s0[i], LOG2E, ESHIFT));
                e[i + 4] = __builtin_amdgcn_exp2f(__builtin_fmaf(s1[i], LOG2E, ESHIFT));
            }
            if (kt == 0)
                rs += ((e[0] + e[1]) + (e[2] + e[3])) + ((e[4] + e[5]) + (e[6] + e[7]));
            union { half8 h8; fp16x2 h2[4]; } u;
            u.h2[0] = __builtin_amdgcn_cvt_pkrtz(e[0], e[1]);
            u.h2[1] = __builtin_amdgcn_cvt_pkrtz(e[2], e[3]);
            u.h2[2] = __builtin_amdgcn_cvt_pkrtz(e[4], e[5]);
            u.h2[3] = __builtin_amdgcn_cvt_pkrtz(e[6], e[7]);
            half8 vb = *(const half8*)&Vt[kt * 16 + lr][kst * 32 + lg * 8];
            oacc = __builtin_amdgcn_mfma_f32_16x16x32_f16(u.h8, vb, oacc, 0, 0, 0);
        }
    }

    // ---- rowsum finalize (kt==0 waves hold lg-group partials) ----
    if (kt == 0) {
        rs += __shfl_xor(rs, 16);
        rs += __shfl_xor(rs, 32);
        if (l < 16) rsumf[qt * 16 + l] = rs;
    }
    __syncthreads();
    if (t < 32) rsumf[t] = 1.0f / rsumf[t];
    __syncthreads();

    // ---- O: scale into Sst, coalesced NT store ----
#pragma unroll
    for (int r = 0; r < 4; ++r)
        Sst[qt * 16 + lg * 4 + r][kt * 16 + lr] =
            oacc[r] * rsumf[qt * 16 + lg * 4 + r];
    __syncthreads();
    {
        f32x4 ov = *(const f32x4*)&Sst[t >> 4][(t & 15) * 4];
        __builtin_nontemporal_store(ov,
            (f32x4*)(out_o + inb + (size_t)(q0 + (t >> 4)) * D + (t & 15) * 4));
    }

    // ---- out_a epilogue: replay own out_s slice (L2/L3-hot), exp*inv, NT ----
    {
        const int   arow = t >> 4;
        const int   ac0  = (t & 15) * 4;
        const float iva  = rsumf[arow];
        const float* sp  = out_s + sb + (size_t)arow * N + ac0;
        float*       ap  = out_a + sb + (size_t)arow * N + ac0;
#pragma unroll 4
        for (int cb = 0; cb < NC; ++cb) {
            f32x4 sv = *(const f32x4*)(sp + cb * TK);
            f32x4 av;
#pragma unroll
            for (int i = 0; i < 4; ++i)
                av[i] = __builtin_amdgcn_exp2f(__builtin_fmaf(sv[i], LOG2E, ESHIFT)) * iva;
            __builtin_nontemporal_store(av, (f32x4*)(ap + cb * TK));
        }
    }
}

extern "C" void kernel_launch(void* const* d_in, const int* in_sizes, int n_in,
                              void* d_out, int out_size, void* d_ws, size_t ws_size,
                              hipStream_t stream) {
    const float* q  = (const float*)d_in[0];
    const float* k  = (const float*)d_in[1];
    const float* v  = (const float*)d_in[2];
    const float* qs = (const float*)d_in[3];
    const float* ks = (const float*)d_in[4];

    float* out_o = (float*)d_out;                       // [64,1024,64]
    float* out_a = out_o + (size_t)BH * N * D;          // [64,1024,1024]
    float* out_s = out_a + (size_t)BH * N * N;          // [64,1024,1024]

    attn_fused_kernel<<<dim3(BH * (N / 32)), dim3(512), 0, stream>>>(
        q, k, v, qs, ks, out_o, out_a, out_s);
}